// Round 10
// baseline (213.898 us; speedup 1.0000x reference)
//
#include <hip/hip_runtime.h>

#define NN 500000
#define KK 3
#define EE (NN * KK)
#define HH 64
#define NC 8
#define NIN 16
#define EIN 8

typedef __attribute__((ext_vector_type(2))) _Float16 h2;
typedef __attribute__((ext_vector_type(2)))  float sf2;
typedef __attribute__((ext_vector_type(8)))  float sf8;
typedef __attribute__((ext_vector_type(16))) float sf16;

using pk_t = decltype(__builtin_amdgcn_cvt_pkrtz(0.f, 0.f));

// Guaranteed-scalar loads of wave-uniform weight data (K$-cached, scalar pipe).
__device__ __forceinline__ sf2 sload2(const float* p) {
    sf2 r; asm("s_load_dwordx2 %0, %1, 0x0" : "=s"(r) : "s"(p)); return r;
}
__device__ __forceinline__ sf8 sload8(const float* p) {
    sf8 r; asm("s_load_dwordx8 %0, %1, 0x0" : "=s"(r) : "s"(p)); return r;
}
__device__ __forceinline__ sf16 sload16(const float* p) {
    sf16 r; asm("s_load_dwordx16 %0, %1, 0x0" : "=s"(r) : "s"(p)); return r;
}
#define SWAIT1(a)           asm volatile("s_waitcnt lgkmcnt(0)" : "+s"(a))
#define SWAIT2(a,b)         asm volatile("s_waitcnt lgkmcnt(0)" : "+s"(a),"+s"(b))
#define SWAIT3(a,b,c)       asm volatile("s_waitcnt lgkmcnt(0)" : "+s"(a),"+s"(b),"+s"(c))
#define SWAIT5(a,b,c,d,e)   asm volatile("s_waitcnt lgkmcnt(0)" : "+s"(a),"+s"(b),"+s"(c),"+s"(d),"+s"(e))
#define SWAIT6(a,b,c,d,e,f) asm volatile("s_waitcnt lgkmcnt(0)" : "+s"(a),"+s"(b),"+s"(c),"+s"(d),"+s"(e),"+s"(f))

#if __has_builtin(__builtin_elementwise_fma)
#define PKFMA(a,b,c) __builtin_elementwise_fma((a),(b),(c))
#else
#define PKFMA(a,b,c) ((a)*(b)+(c))
#endif

__device__ __forceinline__ h2 bch2(float f)        { return __builtin_bit_cast(h2, f); }
__device__ __forceinline__ h2 bch2u(unsigned int u){ return __builtin_bit_cast(h2, u); }
__device__ __forceinline__ h2 dup16(float f) {
    return __builtin_bit_cast(h2, __builtin_amdgcn_cvt_pkrtz(f, f));
}
__device__ __forceinline__ unsigned int pkrtz_u(float a, float b) {
    return __builtin_bit_cast(unsigned int, __builtin_amdgcn_cvt_pkrtz(a, b));
}
__device__ __forceinline__ h2 splat_lo(unsigned int u) {
    h2 p = bch2u(u); h2 r; r.x = p.x; r.y = p.x; return r;
}
__device__ __forceinline__ h2 splat_hi(unsigned int u) {
    h2 p = bch2u(u); h2 r; r.x = p.y; r.y = p.y; return r;
}
__device__ __forceinline__ float lo_f32(unsigned int u) { return (float)bch2u(u).x; }
__device__ __forceinline__ float hi_f32(unsigned int u) { return (float)bch2u(u).y; }

__device__ __forceinline__ float fdot2(h2 a, h2 b, float c) {
#if __has_builtin(__builtin_amdgcn_fdot2)
    return __builtin_amdgcn_fdot2(__builtin_bit_cast(pk_t, a),
                                  __builtin_bit_cast(pk_t, b), c, false);
#else
    return c + (float)a.x * (float)b.x + (float)a.y * (float)b.y;
#endif
}
__device__ __forceinline__ float lky(float x)  { return fmaxf(x, 0.1f * x); }
__device__ __forceinline__ h2 lk2(h2 x) {
    h2 c = {(_Float16)0.1f, (_Float16)0.1f};
    return __builtin_elementwise_max(x, x * c);
}
__device__ __forceinline__ float pack2(float a, float b) {
    h2 v; v.x = (_Float16)a; v.y = (_Float16)b;   // RTN conversion for weights
    return __builtin_bit_cast(float, v);
}

struct P1 {
    const float *node_feat, *edge_attr; const int* nbr;
    const float *Wn, *bn, *We, *be;
    // layer-0 weight slices (f32, streamed directly)
    const float *mW1, *mb1, *mW2, *mb2, *uW1, *ub1, *uW2, *ub2;
    // layer-1 + final weights (packed into wpack for K2)
    const float *mW1p, *uW1p, *mb1p, *ub1p, *mW2p, *uW2p;
    const float *fW1, *fb1, *fW2;
    unsigned int *hp, *ep; float* wpack;
};

// project a node_feat row (16 f32, one cache line) to (h0,h1)
__device__ __forceinline__ float2 projN(const float* node_feat, int idx,
                                        const sf16& wn0, const sf16& wn1, const sf2& bnv) {
    const float4* x4 = (const float4*)(node_feat + (size_t)idx * NIN);
    float4 v0 = x4[0], v1 = x4[1], v2 = x4[2], v3 = x4[3];
    float xs[16] = {v0.x, v0.y, v0.z, v0.w, v1.x, v1.y, v1.z, v1.w,
                    v2.x, v2.y, v2.z, v2.w, v3.x, v3.y, v3.z, v3.w};
    float a0 = bnv.x, a1 = bnv.y;
#pragma unroll
    for (int i = 0; i < 8; i++) {
        a0 = fmaf(xs[i], wn0[2 * i], a0);
        a1 = fmaf(xs[i], wn0[2 * i + 1], a1);
    }
#pragma unroll
    for (int i = 0; i < 8; i++) {
        a0 = fmaf(xs[8 + i], wn1[2 * i], a0);
        a1 = fmaf(xs[8 + i], wn1[2 * i + 1], a1);
    }
    return make_float2(a0, a1);
}

// ---- K1: projections + layer 0 (f32 math, SGPR-streamed f32 weights) ----
// Also packs layer-1/final f16 weights into wpack (block 0) for K2.
__global__ __launch_bounds__(256) void k1_kernel(P1 P) {
    // ---- weight packing for K2 (block 0; visible to K2 across kernel boundary) ----
    if (blockIdx.x == 0) {
        int t = threadIdx.x;
        if (t < 16) {
            int which = t >> 3, c = t & 7;
            const float* W1 = which ? P.uW1p : P.mW1p;
            const float* b1 = which ? P.ub1p : P.mb1p;
            const float* W2 = which ? P.uW2p : P.mW2p;
            float* dst = P.wpack + (2 + which) * 256 + c * 32;
            int j0 = c * 8;
            for (int r = 0; r < 4; r++)
                for (int p = 0; p < 4; p++)
                    dst[r * 4 + p] = pack2(W1[r * HH + j0 + 2 * p], W1[r * HH + j0 + 2 * p + 1]);
            for (int p = 0; p < 4; p++) {
                dst[16 + p] = pack2(b1[j0 + 2 * p], b1[j0 + 2 * p + 1]);
                dst[20 + p] = pack2(W2[(j0 + 2 * p) * 2 + 0], W2[(j0 + 2 * p + 1) * 2 + 0]);
                dst[24 + p] = pack2(W2[(j0 + 2 * p) * 2 + 1], W2[(j0 + 2 * p + 1) * 2 + 1]);
                dst[28 + p] = 0.0f;
            }
        } else if (t < 24) {
            int c = t - 16, j0 = c * 8;
            float* dst = P.wpack + 1024 + c * 48;
            for (int p = 0; p < 4; p++) {
                dst[p]      = pack2(P.fW1[j0 + 2 * p],      P.fW1[j0 + 2 * p + 1]);
                dst[4 + p]  = pack2(P.fW1[HH + j0 + 2 * p], P.fW1[HH + j0 + 2 * p + 1]);
                dst[8 + p]  = pack2(P.fb1[j0 + 2 * p],      P.fb1[j0 + 2 * p + 1]);
                dst[12 + p] = 0.0f;
            }
            for (int jp = 0; jp < 4; jp++)
                for (int cc = 0; cc < NC; cc++)
                    dst[16 + jp * 8 + cc] = pack2(P.fW2[(j0 + 2 * jp) * NC + cc],
                                                  P.fW2[(j0 + 2 * jp + 1) * NC + cc]);
        }
    }

    int i = blockIdx.x * 256 + threadIdx.x;
    if (i >= NN) return;

    sf16 wn0 = sload16(P.Wn);
    sf16 wn1 = sload16(P.Wn + 16);
    sf2  bnv = sload2(P.bn);
    sf16 wev = sload16(P.We);
    sf2  bev = sload2(P.be);
    SWAIT5(wn0, wn1, bnv, wev, bev);

    int base = i * KK;
    int n0 = P.nbr[base + 0], n1 = P.nbr[base + 1], n2 = P.nbr[base + 2];

    // own h + neighbor h on the fly (each node_feat row = one 64B line)
    float2 hh = projN(P.node_feat, i,  wn0, wn1, bnv);
    float2 g0 = projN(P.node_feat, n0, wn0, wn1, bnv);
    float2 g1 = projN(P.node_feat, n1, wn0, wn1, bnv);
    float2 g2 = projN(P.node_feat, n2, wn0, wn1, bnv);

    // edge projections (coalesced rows), kept f32; also saved packed for K2
    float ex[3], ey[3];
#pragma unroll
    for (int k = 0; k < 3; k++) {
        const float4* x4 = (const float4*)(P.edge_attr + (size_t)(base + k) * EIN);
        float4 v0 = x4[0], v1 = x4[1];
        float xs[8] = {v0.x, v0.y, v0.z, v0.w, v1.x, v1.y, v1.z, v1.w};
        float a0 = bev.x, a1 = bev.y;
#pragma unroll
        for (int q = 0; q < 8; q++) {
            a0 = fmaf(xs[q], wev[2 * q], a0);
            a1 = fmaf(xs[q], wev[2 * q + 1], a1);
        }
        ex[k] = a0; ey[k] = a1;
        P.ep[base + k] = pkrtz_u(a0, a1);
    }

    sf2 mb2v = sload2(P.mb2);
    sf2 ub2v = sload2(P.ub2);
    SWAIT2(mb2v, ub2v);

    // aggr = (sum_e leaky([e,hn]@W1+b1)) @ W2 + 3*b2   (linearity of segment_sum)
    float a0 = 3.0f * mb2v.x, a1 = 3.0f * mb2v.y;
#pragma unroll 1
    for (int j0 = 0; j0 < HH; j0 += 8) {
        sf8 w0 = sload8(P.mW1 + j0);
        sf8 w1 = sload8(P.mW1 + HH + j0);
        sf8 w2 = sload8(P.mW1 + 2 * HH + j0);
        sf8 w3 = sload8(P.mW1 + 3 * HH + j0);
        sf8 bb = sload8(P.mb1 + j0);
        sf16 wc = sload16(P.mW2 + 2 * j0);
        SWAIT6(w0, w1, w2, w3, bb, wc);
#pragma unroll
        for (int q = 0; q < 8; q++) {
            float t0 = fmaf(ex[0], w0[q], fmaf(ey[0], w1[q], fmaf(g0.x, w2[q], fmaf(g0.y, w3[q], bb[q]))));
            float t1 = fmaf(ex[1], w0[q], fmaf(ey[1], w1[q], fmaf(g1.x, w2[q], fmaf(g1.y, w3[q], bb[q]))));
            float t2 = fmaf(ex[2], w0[q], fmaf(ey[2], w1[q], fmaf(g2.x, w2[q], fmaf(g2.y, w3[q], bb[q]))));
            float ts = lky(t0) + lky(t1) + lky(t2);
            a0 = fmaf(ts, wc[2 * q], a0);
            a1 = fmaf(ts, wc[2 * q + 1], a1);
        }
    }

    // update MLP on concat(h, aggr)
    float u0 = ub2v.x, u1 = ub2v.y;
#pragma unroll 1
    for (int j0 = 0; j0 < HH; j0 += 8) {
        sf8 w0 = sload8(P.uW1 + j0);
        sf8 w1 = sload8(P.uW1 + HH + j0);
        sf8 w2 = sload8(P.uW1 + 2 * HH + j0);
        sf8 w3 = sload8(P.uW1 + 3 * HH + j0);
        sf8 bb = sload8(P.ub1 + j0);
        sf16 wc = sload16(P.uW2 + 2 * j0);
        SWAIT6(w0, w1, w2, w3, bb, wc);
#pragma unroll
        for (int q = 0; q < 8; q++) {
            float tt = fmaf(hh.x, w0[q], fmaf(hh.y, w1[q], fmaf(a0, w2[q], fmaf(a1, w3[q], bb[q]))));
            tt = lky(tt);
            u0 = fmaf(tt, wc[2 * q], u0);
            u1 = fmaf(tt, wc[2 * q + 1], u1);
        }
    }
    float nh0 = fmaxf(hh.x + u0, 0.0f);
    float nh1 = fmaxf(hh.y + u1, 0.0f);
    P.hp[i] = pkrtz_u(nh0, nh1);
}

// ---- K2: layer 1 + fused final MLP (f16 packed weights from wpack) ----
__global__ __launch_bounds__(256) void k2_kernel(
    const unsigned int* __restrict__ hp_in, const unsigned int* __restrict__ eP,
    const int* __restrict__ nbr,
    const float* __restrict__ mblk, const float* __restrict__ mb2,
    const float* __restrict__ ublk, const float* __restrict__ ub2,
    const float* __restrict__ fblk, const float* __restrict__ fb2,
    float* __restrict__ out)
{
    int i = blockIdx.x * 256 + threadIdx.x;
    if (i >= NN) return;

    sf2 mb2v = sload2(mb2);
    sf2 ub2v = sload2(ub2);
    SWAIT2(mb2v, ub2v);

    unsigned int hO = hp_in[i];
    int base = i * KK;
    int n0 = nbr[base + 0], n1 = nbr[base + 1], n2 = nbr[base + 2];
    unsigned int g0 = hp_in[n0], g1 = hp_in[n1], g2 = hp_in[n2];
    unsigned int e0 = eP[base + 0], e1 = eP[base + 1], e2 = eP[base + 2];

    h2 e0x = splat_lo(e0), e0y = splat_hi(e0);
    h2 e1x = splat_lo(e1), e1y = splat_hi(e1);
    h2 e2x = splat_lo(e2), e2y = splat_hi(e2);
    h2 n0x = splat_lo(g0), n0y = splat_hi(g0);
    h2 n1x = splat_lo(g1), n1y = splat_hi(g1);
    h2 n2x = splat_lo(g2), n2y = splat_hi(g2);

    float a0 = 3.0f * mb2v.x, a1 = 3.0f * mb2v.y;
#pragma unroll 1
    for (int c = 0; c < 8; c += 2) {
        sf16 A0 = sload16(mblk + c * 32);
        sf16 B0 = sload16(mblk + c * 32 + 16);
        sf16 A1 = sload16(mblk + c * 32 + 32);
        sf16 B1 = sload16(mblk + c * 32 + 48);
        asm volatile("s_waitcnt lgkmcnt(0)" : "+s"(A0), "+s"(B0), "+s"(A1), "+s"(B1));
#pragma unroll
        for (int half = 0; half < 2; half++) {
            const sf16& A = half ? A1 : A0;
            const sf16& B = half ? B1 : B0;
#pragma unroll
            for (int jp = 0; jp < 4; jp++) {
                h2 w0 = bch2(A[jp]), w1 = bch2(A[4 + jp]);
                h2 w2 = bch2(A[8 + jp]), w3 = bch2(A[12 + jp]);
                h2 bb = bch2(B[jp]);
                h2 t0 = PKFMA(e0x, w0, PKFMA(e0y, w1, PKFMA(n0x, w2, PKFMA(n0y, w3, bb))));
                h2 t1 = PKFMA(e1x, w0, PKFMA(e1y, w1, PKFMA(n1x, w2, PKFMA(n1y, w3, bb))));
                h2 t2 = PKFMA(e2x, w0, PKFMA(e2y, w1, PKFMA(n2x, w2, PKFMA(n2y, w3, bb))));
                h2 ts = lk2(t0) + lk2(t1) + lk2(t2);
                a0 = fdot2(ts, bch2(B[4 + jp]), a0);
                a1 = fdot2(ts, bch2(B[8 + jp]), a1);
            }
        }
    }

    h2 hx = splat_lo(hO), hy = splat_hi(hO);
    h2 ax = dup16(a0), ay = dup16(a1);
    float u0 = ub2v.x, u1 = ub2v.y;
#pragma unroll 1
    for (int c = 0; c < 8; c += 2) {
        sf16 A0 = sload16(ublk + c * 32);
        sf16 B0 = sload16(ublk + c * 32 + 16);
        sf16 A1 = sload16(ublk + c * 32 + 32);
        sf16 B1 = sload16(ublk + c * 32 + 48);
        asm volatile("s_waitcnt lgkmcnt(0)" : "+s"(A0), "+s"(B0), "+s"(A1), "+s"(B1));
#pragma unroll
        for (int half = 0; half < 2; half++) {
            const sf16& A = half ? A1 : A0;
            const sf16& B = half ? B1 : B0;
#pragma unroll
            for (int jp = 0; jp < 4; jp++) {
                h2 tt = PKFMA(hx, bch2(A[jp]),
                        PKFMA(hy, bch2(A[4 + jp]),
                        PKFMA(ax, bch2(A[8 + jp]),
                        PKFMA(ay, bch2(A[12 + jp]), bch2(B[jp])))));
                tt = lk2(tt);
                u0 = fdot2(tt, bch2(B[4 + jp]), u0);
                u1 = fdot2(tt, bch2(B[8 + jp]), u1);
            }
        }
    }
    float nh0 = fmaxf(lo_f32(hO) + u0, 0.0f);
    float nh1 = fmaxf(hi_f32(hO) + u1, 0.0f);

    sf8 fb2v = sload8(fb2);
    SWAIT1(fb2v);
    float o[NC];
#pragma unroll
    for (int cc = 0; cc < NC; cc++) o[cc] = fb2v[cc];
    h2 nx = dup16(nh0), ny = dup16(nh1);
#pragma unroll 1
    for (int c = 0; c < 8; c++) {
        sf16 A = sload16(fblk + c * 48);
        sf16 B = sload16(fblk + c * 48 + 16);
        sf16 C = sload16(fblk + c * 48 + 32);
        SWAIT3(A, B, C);
#pragma unroll
        for (int jp = 0; jp < 4; jp++) {
            h2 w1a = bch2(A[jp]), w1b = bch2(A[4 + jp]), bb = bch2(A[8 + jp]);
            h2 tt = lk2(PKFMA(nx, w1a, PKFMA(ny, w1b, bb)));
#pragma unroll
            for (int cc = 0; cc < NC; cc++) {
                float w = (jp < 2) ? B[(jp & 1) * 8 + cc] : C[(jp & 1) * 8 + cc];
                o[cc] = fdot2(tt, bch2(w), o[cc]);
            }
        }
    }
    float4* op = (float4*)(out + (size_t)i * NC);
    op[0] = make_float4(o[0], o[1], o[2], o[3]);
    op[1] = make_float4(o[4], o[5], o[6], o[7]);
}

extern "C" void kernel_launch(void* const* d_in, const int* in_sizes, int n_in,
                              void* d_out, int out_size, void* d_ws, size_t ws_size,
                              hipStream_t stream) {
    const float* node_feat = (const float*)d_in[0];
    const float* edge_attr = (const float*)d_in[1];
    const int* edge_index = (const int*)d_in[2];
    // d_in[3] = batch (unused)
    const float* Wn = (const float*)d_in[4];
    const float* bn = (const float*)d_in[5];
    const float* We = (const float*)d_in[6];
    const float* be = (const float*)d_in[7];
    const float* msgW1 = (const float*)d_in[8];
    const float* msgb1 = (const float*)d_in[9];
    const float* msgW2 = (const float*)d_in[10];
    const float* msgb2 = (const float*)d_in[11];
    const float* updW1 = (const float*)d_in[12];
    const float* updb1 = (const float*)d_in[13];
    const float* updW2 = (const float*)d_in[14];
    const float* updb2 = (const float*)d_in[15];
    const float* finW1 = (const float*)d_in[16];
    const float* finb1 = (const float*)d_in[17];
    const float* finW2 = (const float*)d_in[18];
    const float* finb2 = (const float*)d_in[19];
    float* out = (float*)d_out;

    const int* nbr = edge_index + EE;  // edge_index[1] row

    char* ws = (char*)d_ws;
    unsigned int* hp = (unsigned int*)ws;                        // NN u32 (2 MB)
    unsigned int* ep = (unsigned int*)(ws + (size_t)NN * 4);     // EE u32 (6 MB)
    float* wpack = (float*)(ws + (size_t)NN * 4 + (size_t)EE * 4);

    P1 P;
    P.node_feat = node_feat; P.edge_attr = edge_attr; P.nbr = nbr;
    P.Wn = Wn; P.bn = bn; P.We = We; P.be = be;
    P.mW1 = msgW1;           P.mb1 = msgb1;           P.mW2 = msgW2;           P.mb2 = msgb2;
    P.uW1 = updW1;           P.ub1 = updb1;           P.uW2 = updW2;           P.ub2 = updb2;
    P.mW1p = msgW1 + 4 * HH; P.mb1p = msgb1 + HH;     P.mW2p = msgW2 + 2 * HH;
    P.uW1p = updW1 + 4 * HH; P.ub1p = updb1 + HH;     P.uW2p = updW2 + 2 * HH;
    P.fW1 = finW1; P.fb1 = finb1; P.fW2 = finW2;
    P.hp = hp; P.ep = ep; P.wpack = wpack;

    const int threads = 256;
    int grid = (NN + threads - 1) / threads;
    k1_kernel<<<grid, threads, 0, stream>>>(P);
    k2_kernel<<<grid, threads, 0, stream>>>(
        hp, ep, nbr,
        wpack + 2 * 256, msgb2 + 2,
        wpack + 3 * 256, updb2 + 2,
        wpack + 1024, finb2, out);
}

// Round 11
// 197.008 us; speedup vs baseline: 1.0857x; 1.0857x over previous
//
#include <hip/hip_runtime.h>

#define NN 500000
#define KK 3
#define EE (NN * KK)
#define HH 64
#define NC 8
#define NIN 16
#define EIN 8

typedef __attribute__((ext_vector_type(2))) _Float16 h2;
typedef __attribute__((ext_vector_type(2)))  float sf2;
typedef __attribute__((ext_vector_type(8)))  float sf8;
typedef __attribute__((ext_vector_type(16))) float sf16;

using pk_t = decltype(__builtin_amdgcn_cvt_pkrtz(0.f, 0.f));

#if __has_builtin(__builtin_elementwise_fma)
#define PKFMA(a,b,c) __builtin_elementwise_fma((a),(b),(c))
#else
#define PKFMA(a,b,c) ((a)*(b)+(c))
#endif

__device__ __forceinline__ h2 bch2(float f)        { return __builtin_bit_cast(h2, f); }
__device__ __forceinline__ h2 bch2u(unsigned int u){ return __builtin_bit_cast(h2, u); }
__device__ __forceinline__ h2 dup16(float f) {
    return __builtin_bit_cast(h2, __builtin_amdgcn_cvt_pkrtz(f, f));
}
__device__ __forceinline__ unsigned int pkrtz_u(float a, float b) {
    return __builtin_bit_cast(unsigned int, __builtin_amdgcn_cvt_pkrtz(a, b));
}
__device__ __forceinline__ h2 splat_lo(unsigned int u) {
    h2 p = bch2u(u); h2 r; r.x = p.x; r.y = p.x; return r;
}
__device__ __forceinline__ h2 splat_hi(unsigned int u) {
    h2 p = bch2u(u); h2 r; r.x = p.y; r.y = p.y; return r;
}
__device__ __forceinline__ float lo_f32(unsigned int u) { return (float)bch2u(u).x; }
__device__ __forceinline__ float hi_f32(unsigned int u) { return (float)bch2u(u).y; }

__device__ __forceinline__ float fdot2(h2 a, h2 b, float c) {
#if __has_builtin(__builtin_amdgcn_fdot2)
    return __builtin_amdgcn_fdot2(__builtin_bit_cast(pk_t, a),
                                  __builtin_bit_cast(pk_t, b), c, false);
#else
    return c + (float)a.x * (float)b.x + (float)a.y * (float)b.y;
#endif
}
__device__ __forceinline__ h2 lk2(h2 x) {
    h2 c = {(_Float16)0.1f, (_Float16)0.1f};
    return __builtin_elementwise_max(x, x * c);
}
__device__ __forceinline__ float pack2(float a, float b) {
    h2 v; v.x = (_Float16)a; v.y = (_Float16)b;   // RTN conversion for weights
    return __builtin_bit_cast(float, v);
}

// ---- fused input projections (packed u32 outputs) + inline weight packing ----
// wpack layout: msg/upd block (l*2+which)*256 dwords, 8 chunks x 32 dwords:
//   [0:3]=W1row0 pairs, [4:7]=row1, [8:11]=row2, [12:15]=row3,
//   [16:19]=b1 pairs, [20:23]=W2[:,0] pairs, [24:27]=W2[:,1] pairs, [28:31]=pad
// final block at 1024: 8 chunks x 48 dwords:
//   [0:3]=fW1row0 pairs, [4:7]=row1, [8:11]=fb1 pairs, [12:15]=pad,
//   [16+jp*8+c] = pack(fW2[j0+2jp][c], fW2[j0+2jp+1][c])
__global__ __launch_bounds__(256) void prep_kernel(
    const float* __restrict__ node_feat, const float* __restrict__ edge_attr,
    const float* __restrict__ Wn, const float* __restrict__ bn,
    const float* __restrict__ We, const float* __restrict__ be,
    unsigned int* __restrict__ hp, unsigned int* __restrict__ ep,
    const float* __restrict__ msgW1, const float* __restrict__ msgb1, const float* __restrict__ msgW2,
    const float* __restrict__ updW1, const float* __restrict__ updb1, const float* __restrict__ updW2,
    const float* __restrict__ finW1, const float* __restrict__ finb1, const float* __restrict__ finW2,
    float* __restrict__ wpack)
{
    const sf16* Wn16 = (const sf16*)Wn;
    sf16 wn0 = Wn16[0];
    sf16 wn1 = Wn16[1];
    sf2  bnv = ((const sf2*)bn)[0];
    sf16 wev = ((const sf16*)We)[0];
    sf2  bev = ((const sf2*)be)[0];

    int idx = blockIdx.x * 256 + threadIdx.x;
    if (idx < NN) {
        const float4* x4 = (const float4*)(node_feat + (size_t)idx * NIN);
        float4 v0 = x4[0], v1 = x4[1], v2 = x4[2], v3 = x4[3];
        float xs[16] = {v0.x, v0.y, v0.z, v0.w, v1.x, v1.y, v1.z, v1.w,
                        v2.x, v2.y, v2.z, v2.w, v3.x, v3.y, v3.z, v3.w};
        float a0 = bnv.x, a1 = bnv.y;
#pragma unroll
        for (int i = 0; i < 8; i++) {
            a0 = fmaf(xs[i], wn0[2 * i], a0);
            a1 = fmaf(xs[i], wn0[2 * i + 1], a1);
        }
#pragma unroll
        for (int i = 0; i < 8; i++) {
            a0 = fmaf(xs[8 + i], wn1[2 * i], a0);
            a1 = fmaf(xs[8 + i], wn1[2 * i + 1], a1);
        }
        hp[idx] = pkrtz_u(a0, a1);
    } else if (idx < NN + EE) {
        int eidx = idx - NN;
        const float4* x4 = (const float4*)(edge_attr + (size_t)eidx * EIN);
        float4 v0 = x4[0], v1 = x4[1];
        float xs[8] = {v0.x, v0.y, v0.z, v0.w, v1.x, v1.y, v1.z, v1.w};
        float a0 = bev.x, a1 = bev.y;
#pragma unroll
        for (int i = 0; i < 8; i++) {
            a0 = fmaf(xs[i], wev[2 * i], a0);
            a1 = fmaf(xs[i], wev[2 * i + 1], a1);
        }
        ep[eidx] = pkrtz_u(a0, a1);
    }

    // ---- inline weight packing (block 0 only; tiny serial side-work) ----
    if (blockIdx.x == 0) {
        int t = threadIdx.x;
        if (t < 32) {
            int l = t >> 4, which = (t >> 3) & 1, c = t & 7;
            const float* W1 = (which ? updW1 : msgW1) + l * 4 * HH;
            const float* b1 = (which ? updb1 : msgb1) + l * HH;
            const float* W2 = (which ? updW2 : msgW2) + l * 2 * HH;
            float* dst = wpack + (l * 2 + which) * 256 + c * 32;
            int j0 = c * 8;
            for (int r = 0; r < 4; r++)
                for (int p = 0; p < 4; p++)
                    dst[r * 4 + p] = pack2(W1[r * HH + j0 + 2 * p], W1[r * HH + j0 + 2 * p + 1]);
            for (int p = 0; p < 4; p++) {
                dst[16 + p] = pack2(b1[j0 + 2 * p], b1[j0 + 2 * p + 1]);
                dst[20 + p] = pack2(W2[(j0 + 2 * p) * 2 + 0], W2[(j0 + 2 * p + 1) * 2 + 0]);
                dst[24 + p] = pack2(W2[(j0 + 2 * p) * 2 + 1], W2[(j0 + 2 * p + 1) * 2 + 1]);
                dst[28 + p] = 0.0f;
            }
        } else if (t < 40) {
            int c = t - 32, j0 = c * 8;
            float* dst = wpack + 1024 + c * 48;
            for (int p = 0; p < 4; p++) {
                dst[p]      = pack2(finW1[j0 + 2 * p],      finW1[j0 + 2 * p + 1]);
                dst[4 + p]  = pack2(finW1[HH + j0 + 2 * p], finW1[HH + j0 + 2 * p + 1]);
                dst[8 + p]  = pack2(finb1[j0 + 2 * p],      finb1[j0 + 2 * p + 1]);
                dst[12 + p] = 0.0f;
            }
            for (int jp = 0; jp < 4; jp++)
                for (int cc = 0; cc < NC; cc++)
                    dst[16 + jp * 8 + cc] = pack2(finW2[(j0 + 2 * jp) * NC + cc],
                                                  finW2[(j0 + 2 * jp + 1) * NC + cc]);
        }
    }
}

// ---- one GNN layer; 1 node/thread; weights via PLAIN C++ loads (compiler
// chooses scalarization + its own fine-grained waits / pipelining) ----
template<bool FINAL>
__global__ __launch_bounds__(256) void layer_kernel(
    const unsigned int* __restrict__ hp_in, const unsigned int* __restrict__ eP,
    const int* __restrict__ nbr,
    const float* __restrict__ mblk, const float* __restrict__ mb2,
    const float* __restrict__ ublk, const float* __restrict__ ub2,
    unsigned int* __restrict__ hp_out,
    const float* __restrict__ fblk, const float* __restrict__ fb2,
    float* __restrict__ out)
{
    int i = blockIdx.x * 256 + threadIdx.x;
    if (i >= NN) return;

    sf2 mb2v = ((const sf2*)mb2)[0];
    sf2 ub2v = ((const sf2*)ub2)[0];

    unsigned int hO = hp_in[i];
    int base = i * KK;
    int n0 = nbr[base + 0], n1 = nbr[base + 1], n2 = nbr[base + 2];
    unsigned int g0 = hp_in[n0], g1 = hp_in[n1], g2 = hp_in[n2];
    unsigned int e0 = eP[base + 0], e1 = eP[base + 1], e2 = eP[base + 2];

    h2 e0x = splat_lo(e0), e0y = splat_hi(e0);
    h2 e1x = splat_lo(e1), e1y = splat_hi(e1);
    h2 e2x = splat_lo(e2), e2y = splat_hi(e2);
    h2 n0x = splat_lo(g0), n0y = splat_hi(g0);
    h2 n1x = splat_lo(g1), n1y = splat_hi(g1);
    h2 n2x = splat_lo(g2), n2y = splat_hi(g2);

    const sf16* M = (const sf16*)mblk;   // 2 sf16 per 32-dword chunk
    const sf16* U = (const sf16*)ublk;

    // aggr = (sum_e leaky([e,hn]@W1+b1)) @ W2 + 3*b2  (linearity of segment_sum)
    float a0 = 3.0f * mb2v.x, a1 = 3.0f * mb2v.y;
#pragma unroll 2
    for (int c = 0; c < 8; c++) {
        sf16 A = M[2 * c];
        sf16 B = M[2 * c + 1];
#pragma unroll
        for (int jp = 0; jp < 4; jp++) {
            h2 w0 = bch2(A[jp]), w1 = bch2(A[4 + jp]);
            h2 w2 = bch2(A[8 + jp]), w3 = bch2(A[12 + jp]);
            h2 bb = bch2(B[jp]);
            h2 t0 = PKFMA(e0x, w0, PKFMA(e0y, w1, PKFMA(n0x, w2, PKFMA(n0y, w3, bb))));
            h2 t1 = PKFMA(e1x, w0, PKFMA(e1y, w1, PKFMA(n1x, w2, PKFMA(n1y, w3, bb))));
            h2 t2 = PKFMA(e2x, w0, PKFMA(e2y, w1, PKFMA(n2x, w2, PKFMA(n2y, w3, bb))));
            h2 ts = lk2(t0) + lk2(t1) + lk2(t2);
            a0 = fdot2(ts, bch2(B[4 + jp]), a0);
            a1 = fdot2(ts, bch2(B[8 + jp]), a1);
        }
    }

    // update MLP on concat(h, aggr)
    h2 hx = splat_lo(hO), hy = splat_hi(hO);
    h2 ax = dup16(a0), ay = dup16(a1);
    float u0 = ub2v.x, u1 = ub2v.y;
#pragma unroll 2
    for (int c = 0; c < 8; c++) {
        sf16 A = U[2 * c];
        sf16 B = U[2 * c + 1];
#pragma unroll
        for (int jp = 0; jp < 4; jp++) {
            h2 tt = PKFMA(hx, bch2(A[jp]),
                    PKFMA(hy, bch2(A[4 + jp]),
                    PKFMA(ax, bch2(A[8 + jp]),
                    PKFMA(ay, bch2(A[12 + jp]), bch2(B[jp])))));
            tt = lk2(tt);
            u0 = fdot2(tt, bch2(B[4 + jp]), u0);
            u1 = fdot2(tt, bch2(B[8 + jp]), u1);
        }
    }
    float nh0 = fmaxf(lo_f32(hO) + u0, 0.0f);
    float nh1 = fmaxf(hi_f32(hO) + u1, 0.0f);

    if constexpr (!FINAL) {
        hp_out[i] = pkrtz_u(nh0, nh1);
    } else {
        sf8 fb2v = ((const sf8*)fb2)[0];
        float o[NC];
#pragma unroll
        for (int cc = 0; cc < NC; cc++) o[cc] = fb2v[cc];
        h2 nx = dup16(nh0), ny = dup16(nh1);
#pragma unroll 2
        for (int c = 0; c < 8; c++) {
            const float* F = fblk + c * 48;
            sf16 A = ((const sf16*)F)[0];
            sf16 B = ((const sf16*)F)[1];
            sf16 C = ((const sf16*)F)[2];
#pragma unroll
            for (int jp = 0; jp < 4; jp++) {
                h2 w1a = bch2(A[jp]), w1b = bch2(A[4 + jp]), bb = bch2(A[8 + jp]);
                h2 tt = lk2(PKFMA(nx, w1a, PKFMA(ny, w1b, bb)));
#pragma unroll
                for (int cc = 0; cc < NC; cc++) {
                    float w = (jp < 2) ? B[(jp & 1) * 8 + cc] : C[(jp & 1) * 8 + cc];
                    o[cc] = fdot2(tt, bch2(w), o[cc]);
                }
            }
        }
        float4* op = (float4*)(out + (size_t)i * NC);
        op[0] = make_float4(o[0], o[1], o[2], o[3]);
        op[1] = make_float4(o[4], o[5], o[6], o[7]);
    }
}

extern "C" void kernel_launch(void* const* d_in, const int* in_sizes, int n_in,
                              void* d_out, int out_size, void* d_ws, size_t ws_size,
                              hipStream_t stream) {
    const float* node_feat = (const float*)d_in[0];
    const float* edge_attr = (const float*)d_in[1];
    const int* edge_index = (const int*)d_in[2];
    // d_in[3] = batch (unused)
    const float* Wn = (const float*)d_in[4];
    const float* bn = (const float*)d_in[5];
    const float* We = (const float*)d_in[6];
    const float* be = (const float*)d_in[7];
    const float* msgW1 = (const float*)d_in[8];
    const float* msgb1 = (const float*)d_in[9];
    const float* msgW2 = (const float*)d_in[10];
    const float* msgb2 = (const float*)d_in[11];
    const float* updW1 = (const float*)d_in[12];
    const float* updb1 = (const float*)d_in[13];
    const float* updW2 = (const float*)d_in[14];
    const float* updb2 = (const float*)d_in[15];
    const float* finW1 = (const float*)d_in[16];
    const float* finb1 = (const float*)d_in[17];
    const float* finW2 = (const float*)d_in[18];
    const float* finb2 = (const float*)d_in[19];
    float* out = (float*)d_out;

    const int* nbr = edge_index + EE;  // edge_index[1] row

    char* ws = (char*)d_ws;
    unsigned int* hA = (unsigned int*)ws;                         // NN u32 (2 MB)
    unsigned int* hB = (unsigned int*)(ws + (size_t)NN * 4);      // NN u32 (2 MB)
    unsigned int* eP = (unsigned int*)(ws + (size_t)NN * 8);      // EE u32 (6 MB)
    float* wpack = (float*)(ws + (size_t)NN * 8 + (size_t)EE * 4);// ~5.6 KB

    const int threads = 256;
    int prep_grid = (NN + EE + threads - 1) / threads;
    prep_kernel<<<prep_grid, threads, 0, stream>>>(
        node_feat, edge_attr, Wn, bn, We, be, hA, eP,
        msgW1, msgb1, msgW2, updW1, updb1, updW2,
        finW1, finb1, finW2, wpack);

    int grid = (NN + threads - 1) / threads;
    // wpack blocks: (l*2 + which)*256 dwords; final at 1024
    layer_kernel<false><<<grid, threads, 0, stream>>>(
        hA, eP, nbr,
        wpack + 0 * 256, msgb2,
        wpack + 1 * 256, updb2,
        hB, wpack + 1024, finb2, nullptr);
    layer_kernel<true><<<grid, threads, 0, stream>>>(
        hB, eP, nbr,
        wpack + 2 * 256, msgb2 + 2,
        wpack + 3 * 256, updb2 + 2,
        nullptr, wpack + 1024, finb2, out);
}

// Round 13
// 189.778 us; speedup vs baseline: 1.1271x; 1.0381x over previous
//
#include <hip/hip_runtime.h>

#define NN 500000
#define KK 3
#define EE (NN * KK)
#define HH 64
#define NC 8
#define NIN 16
#define EIN 8

typedef __attribute__((ext_vector_type(2))) _Float16 h2;
typedef __attribute__((ext_vector_type(2)))  float sf2;
typedef __attribute__((ext_vector_type(8)))  float sf8;
typedef __attribute__((ext_vector_type(16))) float sf16;

using pk_t = decltype(__builtin_amdgcn_cvt_pkrtz(0.f, 0.f));

#if __has_builtin(__builtin_elementwise_fma)
#define PKFMA(a,b,c) __builtin_elementwise_fma((a),(b),(c))
#else
#define PKFMA(a,b,c) ((a)*(b)+(c))
#endif

__device__ __forceinline__ h2 bch2(float f)        { return __builtin_bit_cast(h2, f); }
__device__ __forceinline__ h2 bch2u(unsigned int u){ return __builtin_bit_cast(h2, u); }
__device__ __forceinline__ h2 dup16(float f) {
    return __builtin_bit_cast(h2, __builtin_amdgcn_cvt_pkrtz(f, f));
}
__device__ __forceinline__ unsigned int pkrtz_u(float a, float b) {
    return __builtin_bit_cast(unsigned int, __builtin_amdgcn_cvt_pkrtz(a, b));
}
__device__ __forceinline__ h2 splat_lo(unsigned int u) {
    h2 p = bch2u(u); h2 r; r.x = p.x; r.y = p.x; return r;
}
__device__ __forceinline__ h2 splat_hi(unsigned int u) {
    h2 p = bch2u(u); h2 r; r.x = p.y; r.y = p.y; return r;
}
__device__ __forceinline__ float lo_f32(unsigned int u) { return (float)bch2u(u).x; }
__device__ __forceinline__ float hi_f32(unsigned int u) { return (float)bch2u(u).y; }

__device__ __forceinline__ float fdot2(h2 a, h2 b, float c) {
#if __has_builtin(__builtin_amdgcn_fdot2)
    return __builtin_amdgcn_fdot2(__builtin_bit_cast(pk_t, a),
                                  __builtin_bit_cast(pk_t, b), c, false);
#else
    return c + (float)a.x * (float)b.x + (float)a.y * (float)b.y;
#endif
}
__device__ __forceinline__ h2 lk2(h2 x) {
    h2 c = {(_Float16)0.1f, (_Float16)0.1f};
    return __builtin_elementwise_max(x, x * c);
}
__device__ __forceinline__ float pack2(float a, float b) {
    h2 v; v.x = (_Float16)a; v.y = (_Float16)b;   // RTN conversion for weights
    return __builtin_bit_cast(float, v);
}

// ---- K1: node projection -> packed h table, + f16 weight packing ----
// wpack layout: msg/upd block (l*2+which)*256 dwords, 8 chunks x 32 dwords:
//   [0:3]=W1row0 pairs, [4:7]=row1, [8:11]=row2, [12:15]=row3,
//   [16:19]=b1 pairs, [20:23]=W2[:,0] pairs, [24:27]=W2[:,1] pairs, [28:31]=pad
// final block at 1024: 8 chunks x 48 dwords:
//   [0:3]=fW1row0 pairs, [4:7]=row1, [8:11]=fb1 pairs, [12:15]=pad,
//   [16+jp*8+c] = pack(fW2[j0+2jp][c], fW2[j0+2jp+1][c])
__global__ __launch_bounds__(256) void prep_kernel(
    const float* __restrict__ node_feat,
    const float* __restrict__ Wn, const float* __restrict__ bn,
    unsigned int* __restrict__ hp,
    const float* __restrict__ msgW1, const float* __restrict__ msgb1, const float* __restrict__ msgW2,
    const float* __restrict__ updW1, const float* __restrict__ updb1, const float* __restrict__ updW2,
    const float* __restrict__ finW1, const float* __restrict__ finb1, const float* __restrict__ finW2,
    float* __restrict__ wpack)
{
    const sf16* Wn16 = (const sf16*)Wn;
    sf16 wn0 = Wn16[0];
    sf16 wn1 = Wn16[1];
    sf2  bnv = ((const sf2*)bn)[0];

    int idx = blockIdx.x * 256 + threadIdx.x;
    if (idx < NN) {
        const float4* x4 = (const float4*)(node_feat + (size_t)idx * NIN);
        float4 v0 = x4[0], v1 = x4[1], v2 = x4[2], v3 = x4[3];
        float xs[16] = {v0.x, v0.y, v0.z, v0.w, v1.x, v1.y, v1.z, v1.w,
                        v2.x, v2.y, v2.z, v2.w, v3.x, v3.y, v3.z, v3.w};
        float a0 = bnv.x, a1 = bnv.y;
#pragma unroll
        for (int i = 0; i < 8; i++) {
            a0 = fmaf(xs[i], wn0[2 * i], a0);
            a1 = fmaf(xs[i], wn0[2 * i + 1], a1);
        }
#pragma unroll
        for (int i = 0; i < 8; i++) {
            a0 = fmaf(xs[8 + i], wn1[2 * i], a0);
            a1 = fmaf(xs[8 + i], wn1[2 * i + 1], a1);
        }
        hp[idx] = pkrtz_u(a0, a1);
    }

    // ---- inline weight packing (block 0 only; tiny serial side-work) ----
    if (blockIdx.x == 0) {
        int t = threadIdx.x;
        if (t < 32) {
            int l = t >> 4, which = (t >> 3) & 1, c = t & 7;
            const float* W1 = (which ? updW1 : msgW1) + l * 4 * HH;
            const float* b1 = (which ? updb1 : msgb1) + l * HH;
            const float* W2 = (which ? updW2 : msgW2) + l * 2 * HH;
            float* dst = wpack + (l * 2 + which) * 256 + c * 32;
            int j0 = c * 8;
            for (int r = 0; r < 4; r++)
                for (int p = 0; p < 4; p++)
                    dst[r * 4 + p] = pack2(W1[r * HH + j0 + 2 * p], W1[r * HH + j0 + 2 * p + 1]);
            for (int p = 0; p < 4; p++) {
                dst[16 + p] = pack2(b1[j0 + 2 * p], b1[j0 + 2 * p + 1]);
                dst[20 + p] = pack2(W2[(j0 + 2 * p) * 2 + 0], W2[(j0 + 2 * p + 1) * 2 + 0]);
                dst[24 + p] = pack2(W2[(j0 + 2 * p) * 2 + 1], W2[(j0 + 2 * p + 1) * 2 + 1]);
                dst[28 + p] = 0.0f;
            }
        } else if (t < 40) {
            int c = t - 32, j0 = c * 8;
            float* dst = wpack + 1024 + c * 48;
            for (int p = 0; p < 4; p++) {
                dst[p]      = pack2(finW1[j0 + 2 * p],      finW1[j0 + 2 * p + 1]);
                dst[4 + p]  = pack2(finW1[HH + j0 + 2 * p], finW1[HH + j0 + 2 * p + 1]);
                dst[8 + p]  = pack2(finb1[j0 + 2 * p],      finb1[j0 + 2 * p + 1]);
                dst[12 + p] = 0.0f;
            }
            for (int jp = 0; jp < 4; jp++)
                for (int cc = 0; cc < NC; cc++)
                    dst[16 + jp * 8 + cc] = pack2(finW2[(j0 + 2 * jp) * NC + cc],
                                                  finW2[(j0 + 2 * jp + 1) * NC + cc]);
        }
    }
}

// ---- K2: layer 0 with inline edge projection (reads edge_attr directly,
// writes packed eP for K3 as early as possible). ----
__global__ __launch_bounds__(256) void layer0_kernel(
    const unsigned int* __restrict__ hp_in,
    const float* __restrict__ edge_attr,
    const float* __restrict__ We, const float* __restrict__ be,
    const int* __restrict__ nbr,
    const float* __restrict__ mblk, const float* __restrict__ mb2,
    const float* __restrict__ ublk, const float* __restrict__ ub2,
    unsigned int* __restrict__ hp_out, unsigned int* __restrict__ ep_out)
{
    int i = blockIdx.x * 256 + threadIdx.x;
    if (i >= NN) return;

    sf16 wev = ((const sf16*)We)[0];
    sf2  bev = ((const sf2*)be)[0];
    sf2  mb2v = ((const sf2*)mb2)[0];
    sf2  ub2v = ((const sf2*)ub2)[0];

    int base = i * KK;

    // inline edge projection first (store eP immediately; f16 copies kept)
    h2 ex[3], ey[3];
#pragma unroll
    for (int k = 0; k < 3; k++) {
        const float4* x4 = (const float4*)(edge_attr + (size_t)(base + k) * EIN);
        float4 v0 = x4[0], v1 = x4[1];
        float xs[8] = {v0.x, v0.y, v0.z, v0.w, v1.x, v1.y, v1.z, v1.w};
        float a0 = bev.x, a1 = bev.y;
#pragma unroll
        for (int q = 0; q < 8; q++) {
            a0 = fmaf(xs[q], wev[2 * q], a0);
            a1 = fmaf(xs[q], wev[2 * q + 1], a1);
        }
        ep_out[base + k] = pkrtz_u(a0, a1);
        ex[k] = dup16(a0); ey[k] = dup16(a1);
    }

    unsigned int hO = hp_in[i];
    int n0 = nbr[base + 0], n1 = nbr[base + 1], n2 = nbr[base + 2];
    unsigned int g0 = hp_in[n0], g1 = hp_in[n1], g2 = hp_in[n2];

    h2 n0x = splat_lo(g0), n0y = splat_hi(g0);
    h2 n1x = splat_lo(g1), n1y = splat_hi(g1);
    h2 n2x = splat_lo(g2), n2y = splat_hi(g2);

    const sf16* M = (const sf16*)mblk;
    const sf16* U = (const sf16*)ublk;

    // aggr = (sum_e leaky([e,hn]@W1+b1)) @ W2 + 3*b2  (linearity of segment_sum)
    float a0 = 3.0f * mb2v.x, a1 = 3.0f * mb2v.y;
#pragma unroll 2
    for (int c = 0; c < 8; c++) {
        sf16 A = M[2 * c];
        sf16 B = M[2 * c + 1];
#pragma unroll
        for (int jp = 0; jp < 4; jp++) {
            h2 w0 = bch2(A[jp]), w1 = bch2(A[4 + jp]);
            h2 w2 = bch2(A[8 + jp]), w3 = bch2(A[12 + jp]);
            h2 bb = bch2(B[jp]);
            h2 t0 = PKFMA(ex[0], w0, PKFMA(ey[0], w1, PKFMA(n0x, w2, PKFMA(n0y, w3, bb))));
            h2 t1 = PKFMA(ex[1], w0, PKFMA(ey[1], w1, PKFMA(n1x, w2, PKFMA(n1y, w3, bb))));
            h2 t2 = PKFMA(ex[2], w0, PKFMA(ey[2], w1, PKFMA(n2x, w2, PKFMA(n2y, w3, bb))));
            h2 ts = lk2(t0) + lk2(t1) + lk2(t2);
            a0 = fdot2(ts, bch2(B[4 + jp]), a0);
            a1 = fdot2(ts, bch2(B[8 + jp]), a1);
        }
    }

    // update MLP on concat(h, aggr)
    h2 hx = splat_lo(hO), hy = splat_hi(hO);
    h2 ax = dup16(a0), ay = dup16(a1);
    float u0 = ub2v.x, u1 = ub2v.y;
#pragma unroll 2
    for (int c = 0; c < 8; c++) {
        sf16 A = U[2 * c];
        sf16 B = U[2 * c + 1];
#pragma unroll
        for (int jp = 0; jp < 4; jp++) {
            h2 tt = PKFMA(hx, bch2(A[jp]),
                    PKFMA(hy, bch2(A[4 + jp]),
                    PKFMA(ax, bch2(A[8 + jp]),
                    PKFMA(ay, bch2(A[12 + jp]), bch2(B[jp])))));
            tt = lk2(tt);
            u0 = fdot2(tt, bch2(B[4 + jp]), u0);
            u1 = fdot2(tt, bch2(B[8 + jp]), u1);
        }
    }
    float nh0 = fmaxf(lo_f32(hO) + u0, 0.0f);
    float nh1 = fmaxf(hi_f32(hO) + u1, 0.0f);
    hp_out[i] = pkrtz_u(nh0, nh1);
}

// ---- K3: layer 1 + fused final MLP ----
__global__ __launch_bounds__(256) void layer1_kernel(
    const unsigned int* __restrict__ hp_in, const unsigned int* __restrict__ eP,
    const int* __restrict__ nbr,
    const float* __restrict__ mblk, const float* __restrict__ mb2,
    const float* __restrict__ ublk, const float* __restrict__ ub2,
    const float* __restrict__ fblk, const float* __restrict__ fb2,
    float* __restrict__ out)
{
    int i = blockIdx.x * 256 + threadIdx.x;
    if (i >= NN) return;

    sf2 mb2v = ((const sf2*)mb2)[0];
    sf2 ub2v = ((const sf2*)ub2)[0];

    unsigned int hO = hp_in[i];
    int base = i * KK;
    int n0 = nbr[base + 0], n1 = nbr[base + 1], n2 = nbr[base + 2];
    unsigned int g0 = hp_in[n0], g1 = hp_in[n1], g2 = hp_in[n2];
    unsigned int e0 = eP[base + 0], e1 = eP[base + 1], e2 = eP[base + 2];

    h2 e0x = splat_lo(e0), e0y = splat_hi(e0);
    h2 e1x = splat_lo(e1), e1y = splat_hi(e1);
    h2 e2x = splat_lo(e2), e2y = splat_hi(e2);
    h2 n0x = splat_lo(g0), n0y = splat_hi(g0);
    h2 n1x = splat_lo(g1), n1y = splat_hi(g1);
    h2 n2x = splat_lo(g2), n2y = splat_hi(g2);

    const sf16* M = (const sf16*)mblk;
    const sf16* U = (const sf16*)ublk;

    float a0 = 3.0f * mb2v.x, a1 = 3.0f * mb2v.y;
#pragma unroll 2
    for (int c = 0; c < 8; c++) {
        sf16 A = M[2 * c];
        sf16 B = M[2 * c + 1];
#pragma unroll
        for (int jp = 0; jp < 4; jp++) {
            h2 w0 = bch2(A[jp]), w1 = bch2(A[4 + jp]);
            h2 w2 = bch2(A[8 + jp]), w3 = bch2(A[12 + jp]);
            h2 bb = bch2(B[jp]);
            h2 t0 = PKFMA(e0x, w0, PKFMA(e0y, w1, PKFMA(n0x, w2, PKFMA(n0y, w3, bb))));
            h2 t1 = PKFMA(e1x, w0, PKFMA(e1y, w1, PKFMA(n1x, w2, PKFMA(n1y, w3, bb))));
            h2 t2 = PKFMA(e2x, w0, PKFMA(e2y, w1, PKFMA(n2x, w2, PKFMA(n2y, w3, bb))));
            h2 ts = lk2(t0) + lk2(t1) + lk2(t2);
            a0 = fdot2(ts, bch2(B[4 + jp]), a0);
            a1 = fdot2(ts, bch2(B[8 + jp]), a1);
        }
    }

    h2 hx = splat_lo(hO), hy = splat_hi(hO);
    h2 ax = dup16(a0), ay = dup16(a1);
    float u0 = ub2v.x, u1 = ub2v.y;
#pragma unroll 2
    for (int c = 0; c < 8; c++) {
        sf16 A = U[2 * c];
        sf16 B = U[2 * c + 1];
#pragma unroll
        for (int jp = 0; jp < 4; jp++) {
            h2 tt = PKFMA(hx, bch2(A[jp]),
                    PKFMA(hy, bch2(A[4 + jp]),
                    PKFMA(ax, bch2(A[8 + jp]),
                    PKFMA(ay, bch2(A[12 + jp]), bch2(B[jp])))));
            tt = lk2(tt);
            u0 = fdot2(tt, bch2(B[4 + jp]), u0);
            u1 = fdot2(tt, bch2(B[8 + jp]), u1);
        }
    }
    float nh0 = fmaxf(lo_f32(hO) + u0, 0.0f);
    float nh1 = fmaxf(hi_f32(hO) + u1, 0.0f);

    sf8 fb2v = ((const sf8*)fb2)[0];
    float o[NC];
#pragma unroll
    for (int cc = 0; cc < NC; cc++) o[cc] = fb2v[cc];
    h2 nx = dup16(nh0), ny = dup16(nh1);
#pragma unroll 2
    for (int c = 0; c < 8; c++) {
        const float* F = fblk + c * 48;
        sf16 A = ((const sf16*)F)[0];
        sf16 B = ((const sf16*)F)[1];
        sf16 C = ((const sf16*)F)[2];
#pragma unroll
        for (int jp = 0; jp < 4; jp++) {
            h2 w1a = bch2(A[jp]), w1b = bch2(A[4 + jp]), bb = bch2(A[8 + jp]);
            h2 tt = lk2(PKFMA(nx, w1a, PKFMA(ny, w1b, bb)));
#pragma unroll
            for (int cc = 0; cc < NC; cc++) {
                float w = (jp < 2) ? B[(jp & 1) * 8 + cc] : C[(jp & 1) * 8 + cc];
                o[cc] = fdot2(tt, bch2(w), o[cc]);
            }
        }
    }
    float4* op = (float4*)(out + (size_t)i * NC);
    op[0] = make_float4(o[0], o[1], o[2], o[3]);
    op[1] = make_float4(o[4], o[5], o[6], o[7]);
}

extern "C" void kernel_launch(void* const* d_in, const int* in_sizes, int n_in,
                              void* d_out, int out_size, void* d_ws, size_t ws_size,
                              hipStream_t stream) {
    const float* node_feat = (const float*)d_in[0];
    const float* edge_attr = (const float*)d_in[1];
    const int* edge_index = (const int*)d_in[2];
    // d_in[3] = batch (unused)
    const float* Wn = (const float*)d_in[4];
    const float* bn = (const float*)d_in[5];
    const float* We = (const float*)d_in[6];
    const float* be = (const float*)d_in[7];
    const float* msgW1 = (const float*)d_in[8];
    const float* msgb1 = (const float*)d_in[9];
    const float* msgW2 = (const float*)d_in[10];
    const float* msgb2 = (const float*)d_in[11];
    const float* updW1 = (const float*)d_in[12];
    const float* updb1 = (const float*)d_in[13];
    const float* updW2 = (const float*)d_in[14];
    const float* updb2 = (const float*)d_in[15];
    const float* finW1 = (const float*)d_in[16];
    const float* finb1 = (const float*)d_in[17];
    const float* finW2 = (const float*)d_in[18];
    const float* finb2 = (const float*)d_in[19];
    float* out = (float*)d_out;

    const int* nbr = edge_index + EE;  // edge_index[1] row

    char* ws = (char*)d_ws;
    unsigned int* hA = (unsigned int*)ws;                         // NN u32 (2 MB)
    unsigned int* hB = (unsigned int*)(ws + (size_t)NN * 4);      // NN u32 (2 MB)
    unsigned int* eP = (unsigned int*)(ws + (size_t)NN * 8);      // EE u32 (6 MB)
    float* wpack = (float*)(ws + (size_t)NN * 8 + (size_t)EE * 4);// ~5.6 KB

    const int threads = 256;
    int grid = (NN + threads - 1) / threads;

    // K1: node projection table + weight packing (32 MB read, 2 MB write)
    prep_kernel<<<grid, threads, 0, stream>>>(
        node_feat, Wn, bn, hA,
        msgW1, msgb1, msgW2, updW1, updb1, updW2,
        finW1, finb1, finW2, wpack);

    // K2: layer 0 + inline edge projection (writes hB and eP)
    layer0_kernel<<<grid, threads, 0, stream>>>(
        hA, edge_attr, We, be, nbr,
        wpack + 0 * 256, msgb2,
        wpack + 1 * 256, updb2,
        hB, eP);

    // K3: layer 1 + fused final MLP
    layer1_kernel<<<grid, threads, 0, stream>>>(
        hB, eP, nbr,
        wpack + 2 * 256, msgb2 + 2,
        wpack + 3 * 256, updb2 + 2,
        wpack + 1024, finb2, out);
}